// Round 1
// baseline (174.851 us; speedup 1.0000x reference)
//
#include <hip/hip_runtime.h>
#include <hip/hip_fp16.h>

#define IN_F 128
#define OUT_F 64
#define NB    256     // node-range buckets, 512 nodes each
#define BSH   9
#define CAP   3840    // per-bucket capacity (lambda=2344, +31 sigma, proven R4-R7)
#define CHUNK 2048    // edges per bin block
#define KPF  136      // Fh k-pitch (bf16 elems)
#define KPW  144      // Wt k-pitch (bf16 elems)

using short8  = __attribute__((ext_vector_type(8))) short;
using float4v = __attribute__((ext_vector_type(4))) float;

static __device__ inline unsigned short f2bf(float x) {
    union { float f; unsigned u; } v; v.f = x;
    unsigned r = (v.u + 0x7fffu + ((v.u >> 16) & 1u)) >> 16;  // RN-even
    return (unsigned short)r;
}

// ---- pass 1: bin edges by dst-range (u32: src | dlocal<<17).
// outdeg computed directly via global atomics (400 KB array, L2-resident,
// avg degree 6 -> negligible same-address contention). This removes the
// entire src-side bucket machinery (bkt_s/gcur_s/hs/bases) from bin+csr.
__global__ __launch_bounds__(256) void bin_kernel(
    const int* __restrict__ src, const int* __restrict__ dst,
    int* __restrict__ gcur_d, int* __restrict__ outdeg,
    unsigned* __restrict__ bkt_d, int E)
{
    __shared__ int hd[NB], based[NB];
    const int tid = threadIdx.x;
    const int e0  = blockIdx.x * CHUNK;

    hd[tid] = 0;
    __syncthreads();

    int sv[8], dv[8];
    #pragma unroll
    for (int j = 0; j < 8; ++j) {
        int i = e0 + j * 256 + tid;          // coalesced
        if (i < E) { sv[j] = src[i]; dv[j] = dst[i]; }
        else       { sv[j] = -1;     dv[j] = -1; }
    }
    #pragma unroll
    for (int j = 0; j < 8; ++j) {
        if (dv[j] >= 0) {
            atomicAdd(&hd[dv[j] >> BSH], 1);
            atomicAdd(&outdeg[sv[j]], 1);    // fire-and-forget global atomic
        }
    }
    __syncthreads();

    int cd = hd[tid];
    based[tid] = cd ? atomicAdd(&gcur_d[tid], cd) : 0;
    hd[tid] = 0;                             // reuse as local cursor
    __syncthreads();

    #pragma unroll
    for (int j = 0; j < 8; ++j) {
        if (dv[j] >= 0) {
            int bd = dv[j] >> BSH;
            int pd = atomicAdd(&hd[bd], 1) + based[bd];
            if (pd < CAP)
                bkt_d[(size_t)bd * CAP + pd] =
                    (unsigned)sv[j] | ((unsigned)(dv[j] & 511) << 17);  // src < 2^17
        }
    }
}

// ---- pass 2: per-bucket counting sort + off_deg:int2 (start,count).
// The bucket window (<=15 KB) is read twice: histogram pass warms L1 (32 KB/CU,
// 1 block/CU), scatter pass re-reads from L1. This replaces the old rec[15]
// register cache, which was runtime-indexed and therefore spilled to scratch
// (~600K scratch writes + reads across the grid).
__global__ __launch_bounds__(256) void csr_kernel(
    const unsigned* __restrict__ bkt_d, const int* __restrict__ gcur_d,
    int2* __restrict__ off_deg, int* __restrict__ ebuf)
{
    __shared__ int hist[512], curs[512];
    __shared__ int wsum[4];
    const int b = blockIdx.x, tid = threadIdx.x;
    const int cnt = min(gcur_d[b], CAP);

    hist[tid] = 0; hist[tid + 256] = 0;
    __syncthreads();

    const unsigned* bp = bkt_d + (size_t)b * CAP;
    for (int i = tid; i < cnt; i += 256)
        atomicAdd(&hist[bp[i] >> 17], 1);
    __syncthreads();

    // exclusive scan of hist[512]: wave shuffle scan (no barriers) + combine
    int a0 = hist[2 * tid], a1 = hist[2 * tid + 1];
    int psum = a0 + a1;
    const int lane = tid & 63, w = tid >> 6;
    int x = psum;
    #pragma unroll
    for (int off = 1; off < 64; off <<= 1) {
        int y = __shfl_up(x, off);
        if (lane >= off) x += y;
    }
    if (lane == 63) wsum[w] = x;
    __syncthreads();
    int wbase = 0;
    for (int i = 0; i < w; ++i) wbase += wsum[i];
    int excl = x + wbase - psum;
    curs[2 * tid]     = excl;
    curs[2 * tid + 1] = excl + a0;
    off_deg[b * 512 + 2 * tid]     = make_int2(b * CAP + excl,      a0);
    off_deg[b * 512 + 2 * tid + 1] = make_int2(b * CAP + excl + a0, a1);
    __syncthreads();

    // sorted scatter straight to global (region is L2-resident, lines merge)
    for (int i = tid; i < cnt; i += 256) {
        unsigned e = bp[i];
        int p = atomicAdd(&curs[e >> 17], 1);
        if (p < CAP) ebuf[b * CAP + p] = (int)(e & 0x1FFFFu);
    }
}

// ---- fused GEMM + norm_src via bf16 MFMA (verified R5) ----------------------
__global__ __launch_bounds__(256) void gemm_norm_kernel(
    const float* __restrict__ feat,
    const float* __restrict__ W,
    const int*   __restrict__ outdeg,
    __half* __restrict__ h,
    int n)
{
    __shared__ unsigned short Fh[128 * KPF];  // 34816 B
    __shared__ unsigned short Wt[64 * KPW];   // 18432 B

    const int tid  = threadIdx.x;
    const int row0 = blockIdx.x * 128;

    {
        const float4* W4 = (const float4*)W;
        #pragma unroll
        for (int it = 0; it < 8; ++it) {
            int i4 = it * 256 + tid;
            int k  = i4 >> 4;
            int c4 = (i4 & 15) * 4;
            float4 wv = W4[i4];
            Wt[(c4 + 0) * KPW + k] = f2bf(wv.x);
            Wt[(c4 + 1) * KPW + k] = f2bf(wv.y);
            Wt[(c4 + 2) * KPW + k] = f2bf(wv.z);
            Wt[(c4 + 3) * KPW + k] = f2bf(wv.w);
        }
    }
    {
        const float4* F4 = (const float4*)feat;
        #pragma unroll
        for (int it = 0; it < 16; ++it) {
            int i4 = it * 256 + tid;
            int r  = i4 >> 5;
            int c4 = (i4 & 31) * 4;
            int gr = row0 + r; if (gr >= n) gr = n - 1;
            float4 v = F4[(long)gr * 32 + (i4 & 31)];
            ushort4 u;
            u.x = f2bf(v.x); u.y = f2bf(v.y); u.z = f2bf(v.z); u.w = f2bf(v.w);
            *(ushort4*)&Fh[r * KPF + c4] = u;
        }
    }
    __syncthreads();

    const int w  = tid >> 6;
    const int l  = tid & 63;
    const int ml = l & 15;
    const int q  = l >> 4;

    float4v acc[2][4];
    #pragma unroll
    for (int rt = 0; rt < 2; ++rt)
        #pragma unroll
        for (int ct = 0; ct < 4; ++ct)
            acc[rt][ct] = (float4v){0.f, 0.f, 0.f, 0.f};

    #pragma unroll
    for (int ks = 0; ks < 4; ++ks) {
        const int ko = ks * 32 + q * 8;
        short8 a0 = *(const short8*)&Fh[(w * 32 +  0 + ml) * KPF + ko];
        short8 a1 = *(const short8*)&Fh[(w * 32 + 16 + ml) * KPF + ko];
        short8 b0 = *(const short8*)&Wt[( 0 + ml) * KPW + ko];
        short8 b1 = *(const short8*)&Wt[(16 + ml) * KPW + ko];
        short8 b2 = *(const short8*)&Wt[(32 + ml) * KPW + ko];
        short8 b3 = *(const short8*)&Wt[(48 + ml) * KPW + ko];
        acc[0][0] = __builtin_amdgcn_mfma_f32_16x16x32_bf16(a0, b0, acc[0][0], 0, 0, 0);
        acc[0][1] = __builtin_amdgcn_mfma_f32_16x16x32_bf16(a0, b1, acc[0][1], 0, 0, 0);
        acc[0][2] = __builtin_amdgcn_mfma_f32_16x16x32_bf16(a0, b2, acc[0][2], 0, 0, 0);
        acc[0][3] = __builtin_amdgcn_mfma_f32_16x16x32_bf16(a0, b3, acc[0][3], 0, 0, 0);
        acc[1][0] = __builtin_amdgcn_mfma_f32_16x16x32_bf16(a1, b0, acc[1][0], 0, 0, 0);
        acc[1][1] = __builtin_amdgcn_mfma_f32_16x16x32_bf16(a1, b1, acc[1][1], 0, 0, 0);
        acc[1][2] = __builtin_amdgcn_mfma_f32_16x16x32_bf16(a1, b2, acc[1][2], 0, 0, 0);
        acc[1][3] = __builtin_amdgcn_mfma_f32_16x16x32_bf16(a1, b3, acc[1][3], 0, 0, 0);
    }

    #pragma unroll
    for (int rt = 0; rt < 2; ++rt) {
        #pragma unroll
        for (int reg = 0; reg < 4; ++reg) {
            int row = row0 + w * 32 + rt * 16 + q * 4 + reg;
            if (row < n) {
                float ns = rsqrtf(fmaxf((float)outdeg[row], 1.0f));
                #pragma unroll
                for (int ct = 0; ct < 4; ++ct)
                    h[(long)row * OUT_F + ct * 16 + ml] = __float2half(acc[rt][ct][reg] * ns);
            }
        }
    }
}

// ---- pull aggregation: out[d] = rsqrt(indeg) * sum h[src] -------------------
// one wave per dst; eighth-wave per edge: 8 lanes x uint4(16B) = full 128 B row
// in ONE load instruction -> 8 edges in flight per wave per iteration.
__global__ __launch_bounds__(256) void gather_kernel(
    const int* __restrict__ ebuf, const int2* __restrict__ off_deg,
    const __half* __restrict__ h, float* __restrict__ out, int n)
{
    int d = blockIdx.x * 4 + (threadIdx.x >> 6);
    int l = threadIdx.x & 63;
    int o = l >> 3;          // edge stream 0..7
    int t = l & 7;           // covers cols 8t..8t+7
    if (d >= n) return;
    int2 od = off_deg[d];
    int beg = od.x, m = od.y, end = od.x + od.y;
    float a0 = 0.f, a1 = 0.f, a2 = 0.f, a3 = 0.f;
    float a4 = 0.f, a5 = 0.f, a6 = 0.f, a7 = 0.f;
    for (int j = beg + o; j < end; j += 8) {
        int s = ebuf[j];
        union { uint4 u; __half2 h2[4]; } P;
        P.u = *(const uint4*)&h[(long)s * OUT_F + 8 * t];
        float2 f0 = __half22float2(P.h2[0]);
        float2 f1 = __half22float2(P.h2[1]);
        float2 f2 = __half22float2(P.h2[2]);
        float2 f3 = __half22float2(P.h2[3]);
        a0 += f0.x; a1 += f0.y; a2 += f1.x; a3 += f1.y;
        a4 += f2.x; a5 += f2.y; a6 += f3.x; a7 += f3.y;
    }
    #pragma unroll
    for (int mask = 8; mask <= 32; mask <<= 1) {
        a0 += __shfl_xor(a0, mask); a1 += __shfl_xor(a1, mask);
        a2 += __shfl_xor(a2, mask); a3 += __shfl_xor(a3, mask);
        a4 += __shfl_xor(a4, mask); a5 += __shfl_xor(a5, mask);
        a6 += __shfl_xor(a6, mask); a7 += __shfl_xor(a7, mask);
    }
    if (o == 0) {
        float nd = rsqrtf(fmaxf((float)m, 1.0f));
        float4 v0 = make_float4(a0 * nd, a1 * nd, a2 * nd, a3 * nd);
        float4 v1 = make_float4(a4 * nd, a5 * nd, a6 * nd, a7 * nd);
        *(float4*)&out[(long)d * OUT_F + 8 * t]     = v0;
        *(float4*)&out[(long)d * OUT_F + 8 * t + 4] = v1;
    }
}

extern "C" void kernel_launch(void* const* d_in, const int* in_sizes, int n_in,
                              void* d_out, int out_size, void* d_ws, size_t ws_size,
                              hipStream_t stream) {
    const float* feat = (const float*)d_in[0];
    const float* W    = (const float*)d_in[1];
    const int*   src  = (const int*)d_in[2];
    const int*   dst  = (const int*)d_in[3];
    float* out = (float*)d_out;

    const int n = in_sizes[0] / IN_F;     // 100000
    const int E = in_sizes[2];            // 600000

    // ---- workspace layout (~21 MB; ws is ~268 MB) ----
    char* wsb = (char*)d_ws;
    int* gcur_d = (int*)wsb;                              // NB
    int* outdeg = gcur_d + NB;                            // n (contiguous w/ gcur_d for one memset)
    size_t pos = (((size_t)(NB + n)) * 4 + 15) & ~(size_t)15;
    int2* off_deg = (int2*)(wsb + pos);                   // NB*512 int2 (1 MB)
    pos = (pos + (size_t)NB * 512 * 8 + 15) & ~(size_t)15;
    int* ebuf = (int*)(wsb + pos);                        // NB*CAP (3.9 MB)
    pos = (pos + (size_t)NB * CAP * 4 + 15) & ~(size_t)15;
    unsigned* bkt_d = (unsigned*)(wsb + pos);             // NB*CAP u32 (3.9 MB)
    pos = (pos + (size_t)NB * CAP * 4 + 15) & ~(size_t)15;
    __half* h = (__half*)(wsb + pos);                     // n*64 fp16 (12.8 MB)

    hipMemsetAsync(gcur_d, 0, (NB + n) * sizeof(int), stream);

    bin_kernel<<<(E + CHUNK - 1) / CHUNK, 256, 0, stream>>>(src, dst, gcur_d, outdeg,
                                                            bkt_d, E);
    csr_kernel<<<NB, 256, 0, stream>>>(bkt_d, gcur_d, off_deg, ebuf);
    gemm_norm_kernel<<<(n + 127) / 128, 256, 0, stream>>>(feat, W, outdeg, h, n);
    gather_kernel<<<(n + 3) / 4, 256, 0, stream>>>(ebuf, off_deg, h, out, n);
}

// Round 3
// 155.903 us; speedup vs baseline: 1.1215x; 1.1215x over previous
//
#include <hip/hip_runtime.h>
#include <hip/hip_fp16.h>

#define IN_F 128
#define OUT_F 64
#define NB    256     // node-range buckets, 512 nodes each
#define BSH   9
#define CAP   3840    // per-bucket capacity (lambda=2344, +31 sigma, proven R4-R7)
#define CHUNK 2048    // edges per bin block
#define KPF  136      // Fh k-pitch (bf16 elems)
#define KPW  144      // Wt k-pitch (bf16 elems)

using short8  = __attribute__((ext_vector_type(8))) short;
using float4v = __attribute__((ext_vector_type(4))) float;

static __device__ inline unsigned short f2bf(float x) {
    union { float f; unsigned u; } v; v.f = x;
    unsigned r = (v.u + 0x7fffu + ((v.u >> 16) & 1u)) >> 16;  // RN-even
    return (unsigned short)r;
}

// ---- fused pass 1: edge binning (blocks 0..nbin-1)  ||  GEMM (rest) --------
// gemm no longer applies norm_src (moved to gather as per-edge FMA), so it has
// NO dependency on bin/csr -> both run concurrently in one dispatch. LDS is a
// union (53248 B) so the gemm path keeps 3 blocks/CU.
__global__ __launch_bounds__(256) void bin_gemm_kernel(
    const int* __restrict__ src, const int* __restrict__ dst,
    int* __restrict__ gcur_d, int* __restrict__ gcur_s,
    unsigned* __restrict__ bkt_d, unsigned short* __restrict__ bkt_s,
    int E, int nbin,
    const float* __restrict__ feat, const float* __restrict__ W,
    __half* __restrict__ h, int n)
{
    __shared__ union {
        struct { int hd[NB]; int hs[NB]; int based[NB]; int bases[NB]; } bin;
        struct { unsigned short Fh[128 * KPF]; unsigned short Wt[64 * KPW]; } gm;
    } smem;

    const int tid = threadIdx.x;

    if (blockIdx.x < (unsigned)nbin) {
        // ---------------- bin path (proven R0 structure, src-side restored) --
        const int e0 = blockIdx.x * CHUNK;

        smem.bin.hd[tid] = 0; smem.bin.hs[tid] = 0;
        __syncthreads();

        int sv[8], dv[8];
        #pragma unroll
        for (int j = 0; j < 8; ++j) {
            int i = e0 + j * 256 + tid;          // coalesced
            if (i < E) { sv[j] = src[i]; dv[j] = dst[i]; }
            else       { sv[j] = -1;     dv[j] = -1; }
        }
        #pragma unroll
        for (int j = 0; j < 8; ++j) {
            if (dv[j] >= 0) {
                atomicAdd(&smem.bin.hd[dv[j] >> BSH], 1);
                atomicAdd(&smem.bin.hs[sv[j] >> BSH], 1);
            }
        }
        __syncthreads();

        int cd = smem.bin.hd[tid], cs = smem.bin.hs[tid];
        smem.bin.based[tid] = cd ? atomicAdd(&gcur_d[tid], cd) : 0;
        smem.bin.bases[tid] = cs ? atomicAdd(&gcur_s[tid], cs) : 0;
        smem.bin.hd[tid] = 0; smem.bin.hs[tid] = 0;   // reuse as local cursors
        __syncthreads();

        #pragma unroll
        for (int j = 0; j < 8; ++j) {
            if (dv[j] >= 0) {
                int bd = dv[j] >> BSH;
                int pd = atomicAdd(&smem.bin.hd[bd], 1) + smem.bin.based[bd];
                if (pd < CAP)
                    bkt_d[(size_t)bd * CAP + pd] =
                        (unsigned)sv[j] | ((unsigned)(dv[j] & 511) << 17);  // src < 2^17
                int bs = sv[j] >> BSH;
                int ps = atomicAdd(&smem.bin.hs[bs], 1) + smem.bin.bases[bs];
                if (ps < CAP) bkt_s[(size_t)bs * CAP + ps] = (unsigned short)(sv[j] & 511);
            }
        }
        return;
    }

    // ---------------- gemm path: h = feat @ W (raw, fp16; ns applied in gather)
    unsigned short* Fh = smem.gm.Fh;
    unsigned short* Wt = smem.gm.Wt;
    const int row0 = (blockIdx.x - nbin) * 128;

    {
        const float4* W4 = (const float4*)W;
        #pragma unroll
        for (int it = 0; it < 8; ++it) {
            int i4 = it * 256 + tid;
            int k  = i4 >> 4;
            int c4 = (i4 & 15) * 4;
            float4 wv = W4[i4];
            Wt[(c4 + 0) * KPW + k] = f2bf(wv.x);
            Wt[(c4 + 1) * KPW + k] = f2bf(wv.y);
            Wt[(c4 + 2) * KPW + k] = f2bf(wv.z);
            Wt[(c4 + 3) * KPW + k] = f2bf(wv.w);
        }
    }
    {
        const float4* F4 = (const float4*)feat;
        #pragma unroll
        for (int it = 0; it < 16; ++it) {
            int i4 = it * 256 + tid;
            int r  = i4 >> 5;
            int c4 = (i4 & 31) * 4;
            int gr = row0 + r; if (gr >= n) gr = n - 1;
            float4 v = F4[(long)gr * 32 + (i4 & 31)];
            ushort4 u;
            u.x = f2bf(v.x); u.y = f2bf(v.y); u.z = f2bf(v.z); u.w = f2bf(v.w);
            *(ushort4*)&Fh[r * KPF + c4] = u;
        }
    }
    __syncthreads();

    const int w  = tid >> 6;
    const int l  = tid & 63;
    const int ml = l & 15;
    const int q  = l >> 4;

    float4v acc[2][4];
    #pragma unroll
    for (int rt = 0; rt < 2; ++rt)
        #pragma unroll
        for (int ct = 0; ct < 4; ++ct)
            acc[rt][ct] = (float4v){0.f, 0.f, 0.f, 0.f};

    #pragma unroll
    for (int ks = 0; ks < 4; ++ks) {
        const int ko = ks * 32 + q * 8;
        short8 a0 = *(const short8*)&Fh[(w * 32 +  0 + ml) * KPF + ko];
        short8 a1 = *(const short8*)&Fh[(w * 32 + 16 + ml) * KPF + ko];
        short8 b0 = *(const short8*)&Wt[( 0 + ml) * KPW + ko];
        short8 b1 = *(const short8*)&Wt[(16 + ml) * KPW + ko];
        short8 b2 = *(const short8*)&Wt[(32 + ml) * KPW + ko];
        short8 b3 = *(const short8*)&Wt[(48 + ml) * KPW + ko];
        acc[0][0] = __builtin_amdgcn_mfma_f32_16x16x32_bf16(a0, b0, acc[0][0], 0, 0, 0);
        acc[0][1] = __builtin_amdgcn_mfma_f32_16x16x32_bf16(a0, b1, acc[0][1], 0, 0, 0);
        acc[0][2] = __builtin_amdgcn_mfma_f32_16x16x32_bf16(a0, b2, acc[0][2], 0, 0, 0);
        acc[0][3] = __builtin_amdgcn_mfma_f32_16x16x32_bf16(a0, b3, acc[0][3], 0, 0, 0);
        acc[1][0] = __builtin_amdgcn_mfma_f32_16x16x32_bf16(a1, b0, acc[1][0], 0, 0, 0);
        acc[1][1] = __builtin_amdgcn_mfma_f32_16x16x32_bf16(a1, b1, acc[1][1], 0, 0, 0);
        acc[1][2] = __builtin_amdgcn_mfma_f32_16x16x32_bf16(a1, b2, acc[1][2], 0, 0, 0);
        acc[1][3] = __builtin_amdgcn_mfma_f32_16x16x32_bf16(a1, b3, acc[1][3], 0, 0, 0);
    }

    #pragma unroll
    for (int rt = 0; rt < 2; ++rt) {
        #pragma unroll
        for (int reg = 0; reg < 4; ++reg) {
            int row = row0 + w * 32 + rt * 16 + q * 4 + reg;
            if (row < n) {
                #pragma unroll
                for (int ct = 0; ct < 4; ++ct)
                    h[(long)row * OUT_F + ct * 16 + ml] = __float2half(acc[rt][ct][reg]);
            }
        }
    }
}

// ---- pass 2: per-bucket counting sort (records cached in registers) + outdeg
// + off_deg:int2 (start,count). Scatter lands directly in global ebuf.
// Scan is a barrier-free wave shuffle scan (was 16-barrier Hillis-Steele).
__global__ __launch_bounds__(256) void csr_kernel(
    const unsigned* __restrict__ bkt_d, const unsigned short* __restrict__ bkt_s,
    const int* __restrict__ gcur_d, const int* __restrict__ gcur_s,
    int2* __restrict__ off_deg, int* __restrict__ ebuf, int* __restrict__ outdeg, int n)
{
    __shared__ int hist[512], curs[512], hist_s[512];
    __shared__ int wsum[4];
    const int b = blockIdx.x, tid = threadIdx.x;
    const int cnt   = min(gcur_d[b], CAP);
    const int cnt_s = min(gcur_s[b], CAP);

    hist[tid] = 0; hist[tid + 256] = 0;
    hist_s[tid] = 0; hist_s[tid + 256] = 0;
    __syncthreads();

    // read this bucket's records once; histogram dst-locals
    unsigned rec[15];
    int nrec = 0;
    for (int i = tid; i < cnt; i += 256) {
        unsigned e = bkt_d[(size_t)b * CAP + i];
        rec[nrec++] = e;
        atomicAdd(&hist[e >> 17], 1);
    }
    // src-side histogram (outdeg for nodes in this bucket's range)
    for (int i = tid; i < cnt_s; i += 256)
        atomicAdd(&hist_s[bkt_s[(size_t)b * CAP + i]], 1);
    __syncthreads();

    // exclusive scan of hist[512]: wave shuffle scan + cross-wave combine
    int a0 = hist[2 * tid], a1 = hist[2 * tid + 1];
    int psum = a0 + a1;
    const int lane = tid & 63, w = tid >> 6;
    int x = psum;
    #pragma unroll
    for (int off = 1; off < 64; off <<= 1) {
        int y = __shfl_up(x, off);
        if (lane >= off) x += y;
    }
    if (lane == 63) wsum[w] = x;
    __syncthreads();
    int wbase = 0;
    for (int i = 0; i < w; ++i) wbase += wsum[i];
    int excl = x + wbase - psum;
    curs[2 * tid]     = excl;
    curs[2 * tid + 1] = excl + a0;
    off_deg[b * 512 + 2 * tid]     = make_int2(b * CAP + excl,      a0);
    off_deg[b * 512 + 2 * tid + 1] = make_int2(b * CAP + excl + a0, a1);
    __syncthreads();

    // sorted scatter straight to global (region is L2-resident, lines merge)
    for (int j = 0; j < nrec; ++j) {
        unsigned e = rec[j];
        int p = atomicAdd(&curs[e >> 17], 1);
        if (p < CAP) ebuf[b * CAP + p] = (int)(e & 0x1FFFFu);
    }

    // outdeg writeout
    int node = b * 512 + tid;
    if (node < n) outdeg[node] = hist_s[tid];
    node += 256;
    if (node < n) outdeg[node] = hist_s[tid + 256];
}

// ---- pull aggregation: out[d] = rsqrt(indeg) * sum ns[s] * h[s] -------------
// one wave per dst; eighth-wave per edge: 8 lanes x uint4(16B) = full 128 B row
// in ONE load instruction. norm_src applied here as per-edge FMA (outdeg is a
// 400 KB L2-resident table; the 8 lanes of a stream load the same word ->
// broadcast-merged).
__global__ __launch_bounds__(256) void gather_kernel(
    const int* __restrict__ ebuf, const int2* __restrict__ off_deg,
    const int* __restrict__ outdeg,
    const __half* __restrict__ h, float* __restrict__ out, int n)
{
    int d = blockIdx.x * 4 + (threadIdx.x >> 6);
    int l = threadIdx.x & 63;
    int o = l >> 3;          // edge stream 0..7
    int t = l & 7;           // covers cols 8t..8t+7
    if (d >= n) return;
    int2 od = off_deg[d];
    int beg = od.x, m = od.y, end = od.x + od.y;
    float a0 = 0.f, a1 = 0.f, a2 = 0.f, a3 = 0.f;
    float a4 = 0.f, a5 = 0.f, a6 = 0.f, a7 = 0.f;
    for (int j = beg + o; j < end; j += 8) {
        int s = ebuf[j];
        float ns = rsqrtf(fmaxf((float)outdeg[s], 1.0f));
        union { uint4 u; __half2 h2[4]; } P;
        P.u = *(const uint4*)&h[(long)s * OUT_F + 8 * t];
        float2 f0 = __half22float2(P.h2[0]);
        float2 f1 = __half22float2(P.h2[1]);
        float2 f2 = __half22float2(P.h2[2]);
        float2 f3 = __half22float2(P.h2[3]);
        a0 = fmaf(f0.x, ns, a0); a1 = fmaf(f0.y, ns, a1);
        a2 = fmaf(f1.x, ns, a2); a3 = fmaf(f1.y, ns, a3);
        a4 = fmaf(f2.x, ns, a4); a5 = fmaf(f2.y, ns, a5);
        a6 = fmaf(f3.x, ns, a6); a7 = fmaf(f3.y, ns, a7);
    }
    #pragma unroll
    for (int mask = 8; mask <= 32; mask <<= 1) {
        a0 += __shfl_xor(a0, mask); a1 += __shfl_xor(a1, mask);
        a2 += __shfl_xor(a2, mask); a3 += __shfl_xor(a3, mask);
        a4 += __shfl_xor(a4, mask); a5 += __shfl_xor(a5, mask);
        a6 += __shfl_xor(a6, mask); a7 += __shfl_xor(a7, mask);
    }
    if (o == 0) {
        float nd = rsqrtf(fmaxf((float)m, 1.0f));
        float4 v0 = make_float4(a0 * nd, a1 * nd, a2 * nd, a3 * nd);
        float4 v1 = make_float4(a4 * nd, a5 * nd, a6 * nd, a7 * nd);
        *(float4*)&out[(long)d * OUT_F + 8 * t]     = v0;
        *(float4*)&out[(long)d * OUT_F + 8 * t + 4] = v1;
    }
}

extern "C" void kernel_launch(void* const* d_in, const int* in_sizes, int n_in,
                              void* d_out, int out_size, void* d_ws, size_t ws_size,
                              hipStream_t stream) {
    const float* feat = (const float*)d_in[0];
    const float* W    = (const float*)d_in[1];
    const int*   src  = (const int*)d_in[2];
    const int*   dst  = (const int*)d_in[3];
    float* out = (float*)d_out;

    const int n = in_sizes[0] / IN_F;     // 100000
    const int E = in_sizes[2];            // 600000

    // ---- workspace layout (~24 MB; ws is ~268 MB) ----
    char* wsb = (char*)d_ws;
    int* gcur_d = (int*)wsb;                              // NB
    int* gcur_s = gcur_d + NB;                            // NB
    int* outdeg = gcur_s + NB;                            // n
    size_t pos = (((size_t)(2 * NB + n)) * 4 + 15) & ~(size_t)15;
    int2* off_deg = (int2*)(wsb + pos);                   // NB*512 int2 (1 MB)
    pos = (pos + (size_t)NB * 512 * 8 + 15) & ~(size_t)15;
    int* ebuf = (int*)(wsb + pos);                        // NB*CAP (3.9 MB)
    pos = (pos + (size_t)NB * CAP * 4 + 15) & ~(size_t)15;
    unsigned* bkt_d = (unsigned*)(wsb + pos);             // NB*CAP u32 (3.9 MB)
    pos = (pos + (size_t)NB * CAP * 4 + 15) & ~(size_t)15;
    unsigned short* bkt_s = (unsigned short*)(wsb + pos); // NB*CAP u16 (2.0 MB)
    pos = (pos + (size_t)NB * CAP * 2 + 15) & ~(size_t)15;
    __half* h = (__half*)(wsb + pos);                     // n*64 fp16 (12.8 MB)

    hipMemsetAsync(gcur_d, 0, 2 * NB * sizeof(int), stream);

    const int nbin  = (E + CHUNK - 1) / CHUNK;            // 293
    const int ngemm = (n + 127) / 128;                    // 782

    bin_gemm_kernel<<<nbin + ngemm, 256, 0, stream>>>(src, dst, gcur_d, gcur_s,
                                                      bkt_d, bkt_s, E, nbin,
                                                      feat, W, h, n);
    csr_kernel<<<NB, 256, 0, stream>>>(bkt_d, bkt_s, gcur_d, gcur_s,
                                       off_deg, ebuf, outdeg, n);
    gather_kernel<<<(n + 3) / 4, 256, 0, stream>>>(ebuf, off_deg, outdeg, h, out, n);
}